// Round 13
// baseline (463.363 us; speedup 1.0000x reference)
//
#include <hip/hip_runtime.h>

// RNNDecoderP round 13: r8's 4-wave skeleton (best, 286us, register-clean) with a
// REGISTER-NEUTRAL K-quarter remap to halve DS traffic.
// Lane = (es=L&3, kq=(L>>2)&3, row=L>>4). Each lane owns elements e=es+4*row AND
// e+16, K-chunk [8*kq, 8*kq+8). Dots are 8-MAC; combine = circulant DPP ror4+ror8
// (16-lane row ops, legal CDNA). Weight floats/role stay 48 (6 rows x 8) = r8's
// budget, but h-readback drops 4->2 ds_read_b128 in every role.
// w0: L1 recurrence (yd batched float4/4). w1: gx2 producer (lag-1) + y drain (lag-4).
// w2: L2 recurrence (lag-2). w3: MLP head (lag-3), ror1+ror2 row-sum -> 4 partials.

typedef float v2f __attribute__((ext_vector_type(2)));

constexpr int Bn  = 256;
constexpr int Tn  = 2048;
constexpr int Dn  = 64;
constexpr int DBn = 32;
constexpr int Ln  = 2;
constexpr int Gn  = 96;
constexpr int Kc  = 32;     // steps per chunk/phase (multiple of 4)

#if __has_builtin(__builtin_amdgcn_exp2f)
__device__ __forceinline__ float exp2_fast(float x) { return __builtin_amdgcn_exp2f(x); }
#else
__device__ __forceinline__ float exp2_fast(float x) { return exp2f(x); }
#endif
#if __has_builtin(__builtin_amdgcn_rcpf)
__device__ __forceinline__ float rcp_fast(float x) { return __builtin_amdgcn_rcpf(x); }
#else
__device__ __forceinline__ float rcp_fast(float x) { return 1.0f / x; }
#endif

__device__ __forceinline__ float sigmoid_f(float x) {
  return rcp_fast(1.0f + exp2_fast(-1.4426950408889634f * x));
}
__device__ __forceinline__ float tanh_f(float x) {
  return 1.0f - 2.0f * rcp_fast(1.0f + exp2_fast(2.8853900817779268f * x));
}

template <int CTRL>
__device__ __forceinline__ float dpp_add(float x) {
  int y = __builtin_amdgcn_update_dpp(0, __builtin_bit_cast(int, x), CTRL, 0xf, 0xf, true);
  return x + __builtin_bit_cast(float, y);
}
// sum over the 4 K-quarters (lanes es+4*kq, kq=0..3) via circulant ror4+ror8;
// result = full dot in ALL 16 row lanes (4 identical copies per es)
__device__ __forceinline__ float comb48(float x) {
  x = dpp_add<0x124>(x);   // row_ror:4
  x = dpp_add<0x128>(x);   // row_ror:8
  return x;
}

// 8-float quarter-dot (4 v2f)
__device__ __forceinline__ float dot4(const v2f* __restrict__ w, const v2f* __restrict__ h) {
  v2f a = {0.0f, 0.0f}, b = {0.0f, 0.0f};
  a = __builtin_elementwise_fma(w[0], h[0], a);
  b = __builtin_elementwise_fma(w[1], h[1], b);
  a = __builtin_elementwise_fma(w[2], h[2], a);
  b = __builtin_elementwise_fma(w[3], h[3], b);
  a = a + b;
  return a.x + a.y;
}

// load 8 consecutive floats (2 x float4) into v2f[4]
__device__ __forceinline__ void ld8(const float* p, v2f* d) {
  float4 a = ((const float4*)p)[0];
  float4 bq = ((const float4*)p)[1];
  d[0] = (v2f){a.x, a.y};  d[1] = (v2f){a.z, a.w};
  d[2] = (v2f){bq.x, bq.y}; d[3] = (v2f){bq.z, bq.w};
}

__global__ __launch_bounds__(256, 1)
void rnn_decoder(const int* __restrict__ band_ids, const float* __restrict__ dtime,
                 const float* __restrict__ z_last, const float* __restrict__ projW,
                 const float* __restrict__ projB, const float* __restrict__ Wih,
                 const float* __restrict__ Whh, const float* __restrict__ bih,
                 const float* __restrict__ bhh, const float* __restrict__ mW1,
                 const float* __restrict__ mb1, const float* __restrict__ mW2,
                 const float* __restrict__ mb2, float* __restrict__ out) {
  const int b    = blockIdx.x >> 1;
  const int kb   = blockIdx.x & 1;
  const int tid  = threadIdx.x;              // 0..255
  const int w    = tid >> 6;                 // wave role
  const int L    = tid & 63;
  const int row  = L >> 4;                   // 16-lane DPP row
  const int kq   = (L >> 2) & 3;             // K-quarter
  const int e    = (L & 3) | (row << 2);     // element slot A (0..15); B = e+16
  const int ko   = kq * 8;                   // K offset (8 floats)

  __shared__ __align__(16) float yd[Tn];               // compacted dtime -> y
  __shared__ __align__(16) float gxr_[2][Kc][DBn][4];  // w1 -> w2 packed input gates
  __shared__ __align__(16) float h1r_[2][Kc][DBn];     // w0 -> w1 ring
  __shared__ __align__(16) float h2r_[2][Kc][DBn];     // w2 -> w3 ring (+ own readback)
  __shared__ __align__(16) float vr_[2][Kc][4];        // w3 -> w1 y-partials (per row)
  __shared__ __align__(16) float xb[DBn], xs[DBn];
  __shared__ __align__(16) float y0f[4];               // MLP(h2=0) partials (n==0)
  __shared__ int nsh;

  const float mb2v = mb2[kb];

  if (w == 0) {
    // ======== setup: compaction, proj fold, affine consts, Whh1 slices ========
    {
      const int*   brow = band_ids + b * Tn;
      const float* drow = dtime    + b * Tn;
      int cnt = 0;
      int4 bcache[8];
      #pragma unroll
      for (int it = 0; it < 8; ++it) {
        int4 v = ((const int4*)(brow + L * 32))[it];
        bcache[it] = v;
        cnt += (v.x == kb) + (v.y == kb) + (v.z == kb) + (v.w == kb);
      }
      int incl = cnt;
      #pragma unroll
      for (int dlt = 1; dlt < 64; dlt <<= 1) {
        int v = __shfl_up(incl, dlt, 64);
        if (L >= dlt) incl += v;
      }
      int off = incl - cnt;
      const int n0 = __shfl(incl, 63, 64);
      #pragma unroll
      for (int it = 0; it < 8; ++it) {
        int4   v  = bcache[it];
        float4 dd = ((const float4*)(drow + L * 32))[it];
        if (v.x == kb) yd[off++] = dd.x;
        if (v.y == kb) yd[off++] = dd.y;
        if (v.z == kb) yd[off++] = dd.z;
        if (v.w == kb) yd[off++] = dd.w;
      }
      if (L == 0) nsh = n0;
    }
    {
      const float* zl = z_last + b * Dn;
      #pragma unroll
      for (int s = 0; s < 2; ++s) {
        const int ee = e + 16 * s;
        const float* pw = projW + (kb * (Dn + 1)) * DBn + ee;
        float acc = 0.0f;
        #pragma unroll 8
        for (int k = 0; k < Dn; ++k) acc = fmaf(zl[k], pw[k * DBn], acc);
        xb[ee] = acc + projB[kb * DBn + ee];   // 4x same-addr dup (kq copies)
        xs[ee] = pw[Dn * DBn];
      }
    }
    __builtin_amdgcn_wave_barrier();
    const float* wih1  = Wih + ((kb * Ln + 0) * Gn) * DBn;
    const float* bih1p = bih + (kb * Ln + 0) * Gn;
    const float* bhh1p = bhh + (kb * Ln + 0) * Gn;
    float gb_r0 = 0, gb_z0 = 0, gb_n0 = 0, gs_r0 = 0, gs_z0 = 0, gs_n0 = 0;
    float gb_r1 = 0, gb_z1 = 0, gb_n1 = 0, gs_r1 = 0, gs_z1 = 0, gs_n1 = 0;
    #pragma unroll 4
    for (int j = 0; j < DBn; ++j) {
      float xbv = xb[j], xsv = xs[j];
      float a0 = wih1[(      e) * DBn + j];
      float a1 = wih1[(32 +  e) * DBn + j];
      float a2 = wih1[(64 +  e) * DBn + j];
      float b0 = wih1[(16 +  e) * DBn + j];
      float b1 = wih1[(48 +  e) * DBn + j];
      float b2 = wih1[(80 +  e) * DBn + j];
      gb_r0 = fmaf(a0, xbv, gb_r0);  gs_r0 = fmaf(a0, xsv, gs_r0);
      gb_z0 = fmaf(a1, xbv, gb_z0);  gs_z0 = fmaf(a1, xsv, gs_z0);
      gb_n0 = fmaf(a2, xbv, gb_n0);  gs_n0 = fmaf(a2, xsv, gs_n0);
      gb_r1 = fmaf(b0, xbv, gb_r1);  gs_r1 = fmaf(b0, xsv, gs_r1);
      gb_z1 = fmaf(b1, xbv, gb_z1);  gs_z1 = fmaf(b1, xsv, gs_z1);
      gb_n1 = fmaf(b2, xbv, gb_n1);  gs_n1 = fmaf(b2, xsv, gs_n1);
    }
    gb_r0 += bih1p[e]      + bhh1p[e];
    gb_z0 += bih1p[32 + e] + bhh1p[32 + e];
    gb_n0 += bih1p[64 + e];
    gb_r1 += bih1p[16 + e] + bhh1p[16 + e];
    gb_z1 += bih1p[48 + e] + bhh1p[48 + e];
    gb_n1 += bih1p[80 + e];
    const float bhh1n0 = bhh1p[64 + e];
    const float bhh1n1 = bhh1p[80 + e];
    v2f w1r0[4], w1z0[4], w1n0[4], w1r1[4], w1z1[4], w1n1[4];
    const float* whh1 = Whh + ((kb * Ln + 0) * Gn) * DBn;
    ld8(whh1 + (      e) * DBn + ko, w1r0);
    ld8(whh1 + (32 +  e) * DBn + ko, w1z0);
    ld8(whh1 + (64 +  e) * DBn + ko, w1n0);
    ld8(whh1 + (16 +  e) * DBn + ko, w1r1);
    ld8(whh1 + (48 +  e) * DBn + ko, w1z1);
    ld8(whh1 + (80 +  e) * DBn + ko, w1n1);
    __syncthreads();   // barrier A

#if __has_builtin(__builtin_amdgcn_s_setprio)
    __builtin_amdgcn_s_setprio(1);
#endif
    const int n = nsh;
    const int C = (n + Kc - 1) >> 5;
    v2f h1a[4];
    #pragma unroll
    for (int q = 0; q < 4; ++q) h1a[q] = (v2f){0.0f, 0.0f};
    float h1s0 = 0.0f, h1s1 = 0.0f;
    for (int c = 0; c < C + 4; ++c) {
      if (c < C) {
        float* ring = &h1r_[c & 1][0][0];
        const int t0 = c * Kc;
        for (int k = 0; k < Kc; k += 4) {
          float4 d4 = *(const float4*)&yd[t0 + k];
          #pragma unroll
          for (int u = 0; u < 4; ++u) {
            float d  = (u == 0) ? d4.x : (u == 1) ? d4.y : (u == 2) ? d4.z : d4.w;
            float ar0 = comb48(dot4(w1r0, h1a));
            float az0 = comb48(dot4(w1z0, h1a));
            float an0 = comb48(dot4(w1n0, h1a));
            float ar1 = comb48(dot4(w1r1, h1a));
            float az1 = comb48(dot4(w1z1, h1a));
            float an1 = comb48(dot4(w1n1, h1a));
            float r10 = sigmoid_f(fmaf(d, gs_r0, gb_r0) + ar0);
            float z10 = sigmoid_f(fmaf(d, gs_z0, gb_z0) + az0);
            float n10 = tanh_f(fmaf(d, gs_n0, gb_n0) + r10 * (an0 + bhh1n0));
            float r11v = sigmoid_f(fmaf(d, gs_r1, gb_r1) + ar1);
            float z11v = sigmoid_f(fmaf(d, gs_z1, gb_z1) + az1);
            float n11v = tanh_f(fmaf(d, gs_n1, gb_n1) + r11v * (an1 + bhh1n1));
            h1s0 = fmaf(z10,  h1s0 - n10,  n10);
            h1s1 = fmaf(z11v, h1s1 - n11v, n11v);
            ring[(k + u) * DBn + e]      = h1s0;   // 4x same-addr dup writes
            ring[(k + u) * DBn + e + 16] = h1s1;
            __builtin_amdgcn_wave_barrier();
            ld8(&ring[(k + u) * DBn + ko], h1a);   // 2 b128 (was 4)
          }
        }
      }
      __syncthreads();
    }
  } else if (w == 1) {
    // ======== setup: Wih2 quarter-rows for both element slots ========
    const float* wih2 = Wih + ((kb * Ln + 1) * Gn) * DBn;
    v2f ua0[4], uz0[4], un0[4], ua1[4], uz1[4], un1[4];
    ld8(wih2 + (      e) * DBn + ko, ua0);
    ld8(wih2 + (32 +  e) * DBn + ko, uz0);
    ld8(wih2 + (64 +  e) * DBn + ko, un0);
    ld8(wih2 + (16 +  e) * DBn + ko, ua1);
    ld8(wih2 + (48 +  e) * DBn + ko, uz1);
    ld8(wih2 + (80 +  e) * DBn + ko, un1);
    __syncthreads();   // barrier A

    const int n = nsh;
    const int C = (n + Kc - 1) >> 5;
    for (int c = 0; c < C + 4; ++c) {
      if (c >= 1 && c <= C) {
        const int cp = c - 1;
        const float* hsrc = &h1r_[cp & 1][0][0];
        for (int k = 0; k < Kc; ++k) {
          v2f hb[4];
          ld8(&hsrc[k * DBn + ko], hb);
          float g0 = comb48(dot4(ua0, hb));
          float g1 = comb48(dot4(uz0, hb));
          float g2 = comb48(dot4(un0, hb));
          float g3 = comb48(dot4(ua1, hb));
          float g4 = comb48(dot4(uz1, hb));
          float g5 = comb48(dot4(un1, hb));
          float4 gv0; gv0.x = g0; gv0.y = g1; gv0.z = g2; gv0.w = 0.0f;
          float4 gv1; gv1.x = g3; gv1.y = g4; gv1.z = g5; gv1.w = 0.0f;
          *(float4*)&gxr_[cp & 1][k][e][0]      = gv0;   // 4x dup writes
          *(float4*)&gxr_[cp & 1][k][e + 16][0] = gv1;
        }
      }
      if (c >= 4) {
        const int cd = c - 4;                      // drain y for chunk cd
        if (cd < C && L < 32) {
          float4 p = *(const float4*)&vr_[cd & 1][L][0];
          yd[cd * Kc + L] = ((p.x + p.y) + (p.z + p.w)) + mb2v;
        }
      }
      __syncthreads();
    }
  } else if (w == 2) {
    // ======== setup: Whh2 quarter-rows + bias consts ========
    const float* whh2  = Whh + ((kb * Ln + 1) * Gn) * DBn;
    const float* bih2p = bih + (kb * Ln + 1) * Gn;
    const float* bhh2p = bhh + (kb * Ln + 1) * Gn;
    v2f r2w0[4], z2w0[4], n2w0[4], r2w1[4], z2w1[4], n2w1[4];
    ld8(whh2 + (      e) * DBn + ko, r2w0);
    ld8(whh2 + (32 +  e) * DBn + ko, z2w0);
    ld8(whh2 + (64 +  e) * DBn + ko, n2w0);
    ld8(whh2 + (16 +  e) * DBn + ko, r2w1);
    ld8(whh2 + (48 +  e) * DBn + ko, z2w1);
    ld8(whh2 + (80 +  e) * DBn + ko, n2w1);
    const float c2r0   = bih2p[e]      + bhh2p[e];
    const float c2z0   = bih2p[32 + e] + bhh2p[32 + e];
    const float bih2n0 = bih2p[64 + e];
    const float bhh2n0 = bhh2p[64 + e];
    const float c2r1   = bih2p[16 + e] + bhh2p[16 + e];
    const float c2z1   = bih2p[48 + e] + bhh2p[48 + e];
    const float bih2n1 = bih2p[80 + e];
    const float bhh2n1 = bhh2p[80 + e];
    __syncthreads();   // barrier A

#if __has_builtin(__builtin_amdgcn_s_setprio)
    __builtin_amdgcn_s_setprio(1);
#endif
    const int n = nsh;
    const int C = (n + Kc - 1) >> 5;
    v2f h2a[4];
    #pragma unroll
    for (int q = 0; q < 4; ++q) h2a[q] = (v2f){0.0f, 0.0f};
    float h2s0 = 0.0f, h2s1 = 0.0f;
    for (int c = 0; c < C + 4; ++c) {
      if (c >= 2 && c <= C + 1) {
        const int cc = c - 2;
        float* ring = &h2r_[cc & 1][0][0];
        for (int k = 0; k < Kc; ++k) {
          float4 g0 = *(const float4*)&gxr_[cc & 1][k][e][0];
          float4 g1 = *(const float4*)&gxr_[cc & 1][k][e + 16][0];
          float cr0 = comb48(dot4(r2w0, h2a));
          float cz0 = comb48(dot4(z2w0, h2a));
          float cn0 = comb48(dot4(n2w0, h2a));
          float cr1 = comb48(dot4(r2w1, h2a));
          float cz1 = comb48(dot4(z2w1, h2a));
          float cn1 = comb48(dot4(n2w1, h2a));
          float r20 = sigmoid_f(g0.x + cr0 + c2r0);
          float z20 = sigmoid_f(g0.y + cz0 + c2z0);
          float n20 = tanh_f(g0.z + bih2n0 + r20 * (cn0 + bhh2n0));
          float r21 = sigmoid_f(g1.x + cr1 + c2r1);
          float z21 = sigmoid_f(g1.y + cz1 + c2z1);
          float n21 = tanh_f(g1.z + bih2n1 + r21 * (cn1 + bhh2n1));
          h2s0 = fmaf(z20, h2s0 - n20, n20);
          h2s1 = fmaf(z21, h2s1 - n21, n21);
          ring[k * DBn + e]      = h2s0;
          ring[k * DBn + e + 16] = h2s1;
          __builtin_amdgcn_wave_barrier();
          ld8(&ring[k * DBn + ko], h2a);   // 2 b128 (was 4)
        }
      }
      __syncthreads();
    }
  } else {
    // ======== setup: mW1 quarter-columns for both slots, biases, n==0 fallback ========
    v2f m1c0[4], m1c1[4];
    #pragma unroll
    for (int q = 0; q < 4; ++q) {
      m1c0[q] = (v2f){ mW1[(kb * DBn + ko + 2*q)     * DBn + e],
                       mW1[(kb * DBn + ko + 2*q + 1) * DBn + e] };
      m1c1[q] = (v2f){ mW1[(kb * DBn + ko + 2*q)     * DBn + e + 16],
                       mW1[(kb * DBn + ko + 2*q + 1) * DBn + e + 16] };
    }
    const float mb1e0 = mb1[kb * DBn + e];
    const float mb1e1 = mb1[kb * DBn + e + 16];
    const float mW2e0 = mW2[kb * DBn + e];
    const float mW2e1 = mW2[kb * DBn + e + 16];
    {
      // n==0 fallback: h2 = 0 -> dot = 0
      float v = fmaxf(mb1e0, 0.0f) * mW2e0 + fmaxf(mb1e1, 0.0f) * mW2e1;
      v = dpp_add<0x121>(v);   // ror1
      v = dpp_add<0x122>(v);   // ror2 -> sum over es (kq copies identical)
      if ((L & 15) == 15) y0f[row] = v;
    }
    __syncthreads();   // barrier A

    const int n = nsh;
    const int C = (n + Kc - 1) >> 5;
    for (int c = 0; c < C + 4; ++c) {
      if (c >= 3 && c <= C + 2) {
        const int cm = c - 3;
        if (cm < C) {
          const float* hsrc = &h2r_[cm & 1][0][0];
          for (int k = 0; k < Kc; ++k) {
            v2f hb[4];
            ld8(&hsrc[k * DBn + ko], hb);
            float p0 = comb48(dot4(m1c0, hb));
            float p1 = comb48(dot4(m1c1, hb));
            float v = fmaxf(p0 + mb1e0, 0.0f) * mW2e0 + fmaxf(p1 + mb1e1, 0.0f) * mW2e1;
            v = dpp_add<0x121>(v);
            v = dpp_add<0x122>(v);   // every lane: sum over this row's 8 elements
            if ((L & 15) == 15) vr_[cm & 1][k][row] = v;
          }
        }
      }
      __syncthreads();
    }
  }

  // ================= joint epilogue =================
  const int n = nsh;
  float ylast;
  if (n > 0) {
    ylast = yd[n - 1];
  } else {
    float4 p = *(const float4*)&y0f[0];
    ylast = ((p.x + p.y) + (p.z + p.w)) + mb2v;
  }
  for (int t = n + tid; t < Tn; t += 256) yd[t] = ylast;
  __syncthreads();

  float* orow = out + (kb * Bn + b) * Tn;
  for (int q = tid; q < Tn / 4; q += 256)
    ((float4*)orow)[q] = ((const float4*)yd)[q];
}

extern "C" void kernel_launch(void* const* d_in, const int* in_sizes, int n_in,
                              void* d_out, int out_size, void* d_ws, size_t ws_size,
                              hipStream_t stream) {
  const int*   band_ids = (const int*)  d_in[0];
  const float* dtime    = (const float*)d_in[1];
  const float* z_last   = (const float*)d_in[2];
  const float* projW    = (const float*)d_in[3];
  const float* projB    = (const float*)d_in[4];
  const float* Wih      = (const float*)d_in[5];
  const float* Whh      = (const float*)d_in[6];
  const float* bihp     = (const float*)d_in[7];
  const float* bhhp     = (const float*)d_in[8];
  const float* mW1      = (const float*)d_in[9];
  const float* mb1      = (const float*)d_in[10];
  const float* mW2      = (const float*)d_in[11];
  const float* mb2      = (const float*)d_in[12];
  float* out = (float*)d_out;
  rnn_decoder<<<dim3(Bn * 2), dim3(256), 0, stream>>>(
      band_ids, dtime, z_last, projW, projB, Wih, Whh, bihp, bhhp,
      mW1, mb1, mW2, mb2, out);
}